// Round 12
// baseline (1818.852 us; speedup 1.0000x reference)
//
#include <hip/hip_runtime.h>
#include <math.h>

typedef unsigned long long u64;
typedef unsigned int u32;
typedef unsigned short u16;

// SupervisedClusteringLoss via Borůvka MST.
// r11 post-mortem: build=58us (VALU-bound sorted-insert), but ~265us was 24
// cscan/merge launches at ~11us each (launch + LDS staging overhead, tiny
// work). r12: fuse ALL rounds+count into one 2-block kernel with state in
// LDS (no grid sync needed -- blocks independent); float-gate build inserts.
// Loss invariance: any MST under strict total order (w,lo,hi) has the same
// weight multiset; obj depends only on weights (r7/r9/r11: absmax 0.0).

constexpr int N        = 4096;
constexpr int EDGE_CAP = 4608;
constexpr int ROUNDS   = 12;
constexpr u64 SENT     = ~0ull;

__device__ __forceinline__ u32 mapf(float f) {
    u32 u = __float_as_uint(f);
    return (u & 0x80000000u) ? ~u : (u | 0x80000000u);
}
__device__ __forceinline__ float unmapf(u32 m) {
    u32 u = (m & 0x80000000u) ? (m ^ 0x80000000u) : ~m;
    return __uint_as_float(u);
}

#define INS_STEP(ci) { u64 lo_ = (ci < t) ? ci : t; u64 hi_ = (ci < t) ? t : ci; ci = lo_; t = hi_; }

// One full matrix pass: per-row sorted top-8 candidate list (one wave/row).
__global__ __launch_bounds__(1024, 1)
void bv_build(const float* __restrict__ S, const int* __restrict__ intents,
              u64* __restrict__ cand)
{
    const int g   = blockIdx.y;
    const int tid = threadIdx.x, lane = tid & 63, wid = tid >> 6;
    __shared__ u32 s_ints[N / 4];                    // intents packed u8x4
    for (int d = tid; d < N / 4; d += 1024) {
        const int4 v = *(const int4*)(intents + 4 * d);
        s_ints[d] = (u32)(v.x & 255) | ((u32)(v.y & 255) << 8) |
                    ((u32)(v.z & 255) << 16) | ((u32)(v.w & 255) << 24);
    }
    __syncthreads();
    const int i0   = (int)(s_ints[0] & 255u);
    const int row  = blockIdx.x * 16 + wid;
    const int myii = (int)((s_ints[row >> 2] >> ((row & 3) * 8)) & 255u);
    u64* cp = cand + ((size_t)(g * N + row)) * 8;

    if (g == 0 && myii != i0) {                      // gold: only node-0's class matters
        if (lane == 0) {
            #pragma unroll
            for (int i = 0; i < 8; ++i) cp[i] = SENT;
        }
        return;
    }
    const float* Srow = S + (size_t)row * N;
    u64 c0=SENT,c1=SENT,c2=SENT,c3=SENT,c4=SENT,c5=SENT,c6=SENT,c7=SENT;
    for (int k = 0; k < 16; ++k) {
        const float4 f4 = *(const float4*)(Srow + k * 256 + lane * 4);
        const u32 ip    = s_ints[k * 64 + lane];     // stride-1 -> conflict-free
        const float sv[4] = {f4.x, f4.y, f4.z, f4.w};
        #pragma unroll
        for (int m = 0; m < 4; ++m) {
            const int j   = k * 256 + lane * 4 + m;
            const bool eq = (int)((ip >> (8 * m)) & 255u) == myii;
            float w2; bool ex;
            if (g == 0) { w2 = -sv[m]; ex = eq && (sv[m] != 0.0f); }
            else { const float v = (sv[m] + (eq ? 0.0f : 0.5f)) - (eq ? 1.0f : 0.0f);
                   w2 = -v; ex = (v > 0.0f); }
            ex = ex && (j != row);
            if (ex) {
                const u32 mw = mapf(w2);
                if (mw <= (u32)(c7 >> 32)) {         // float-gate: skip u64 work on miss
                    u64 t = ((u64)mw << 32) | (u32)j;
                    INS_STEP(c0) INS_STEP(c1) INS_STEP(c2) INS_STEP(c3)
                    INS_STEP(c4) INS_STEP(c5) INS_STEP(c6) INS_STEP(c7)
                }
            }
        }
    }
    // extract wave-global top-8 ascending (unique keys -> exactly one popper)
    #pragma unroll
    for (int i = 0; i < 8; ++i) {
        u64 m = c0;
        #pragma unroll
        for (int d2 = 1; d2 < 64; d2 <<= 1) { const u64 o = __shfl_xor(m, d2, 64); if (o < m) m = o; }
        if (c0 == m) { c0=c1; c1=c2; c2=c3; c3=c4; c4=c5; c5=c6; c6=c7; c7=SENT; }
        if (lane == 0) cp[i] = m;
    }
}

// ALL Borůvka rounds + count, one block per graph, state in LDS (~97 KiB).
__global__ __launch_bounds__(1024, 1)
void bv_rounds(const float* __restrict__ S, const int* __restrict__ intents,
               const u64* __restrict__ cand, double* __restrict__ stats)
{
    const int g   = blockIdx.x;
    const int tid = threadIdx.x, lane = tid & 63, wid = tid >> 6;

    __shared__ u16 s_cmp[N];            // 8 KiB  current comp label per node
    __shared__ u64 s_mk[N];             // 32 KiB per-comp min edge key
    __shared__ u16 s_par[N];            // 8 KiB
    __shared__ u64 s_edge[EDGE_CAP];    // 36 KiB selected-edge list
    __shared__ u32 s_ints[N / 4];       // 4 KiB  intents packed u8x4
    __shared__ u32 s_final[N / 32];     // 512 B  finalized-comp bitmask
    __shared__ u16 s_stale[N];          // 8 KiB  rows needing full rescan
    __shared__ int s_stalecnt, s_ecnt, s_merged;
    __shared__ double s_red[16][3];

    for (int d = tid; d < N / 4; d += 1024) {
        const int4 v = *(const int4*)(intents + 4 * d);
        s_ints[d] = (u32)(v.x & 255) | ((u32)(v.y & 255) << 8) |
                    ((u32)(v.z & 255) << 16) | ((u32)(v.w & 255) << 24);
    }
    for (int i = tid; i < N; i += 1024) { s_cmp[i] = (u16)i; s_mk[i] = SENT; }
    for (int i = tid; i < N / 32; i += 1024) s_final[i] = 0;
    if (tid == 0) s_ecnt = 0;
    __syncthreads();
    const int i0 = (int)(s_ints[0] & 255u);

    for (int r = 0; r < ROUNDS; ++r) {
        if (tid == 0) { s_stalecnt = 0; s_merged = 0; }
        __syncthreads();

        // ---- scan from cand lists (threads stride rows)
        for (int i = tid; i < N; i += 1024) {
            const int ii = (int)((s_ints[i >> 2] >> ((i & 3) * 8)) & 255u);
            if (g == 0 && ii != i0) continue;        // gold: exact class skip
            const int c_r = (int)s_cmp[i];
            if ((s_final[c_r >> 5] >> (c_r & 31)) & 1u) continue;
            const u64* cp = cand + ((size_t)(g * N + i)) * 8;
            u64 ksel = SENT; bool end = false;
            #pragma unroll
            for (int q = 0; q < 8; ++q) {
                const u64 k = cp[q];
                const bool isS = (k == SENT);
                if (!end && !isS && ksel == SENT) {
                    const int j = (int)(k & 0xFFFFFFFFu);
                    if ((int)s_cmp[j] != c_r) ksel = k;   // first cross-comp = true min
                }
                end = end || isS;
            }
            if (ksel != SENT) {
                const int j  = (int)(ksel & 0xFFFFFFFFu);
                const u32 wm = (u32)(ksel >> 32);
                const int lo = i < j ? i : j, hi = i < j ? j : i;
                atomicMin(&s_mk[c_r], ((u64)wm << 24) | ((u64)lo << 12) | (u64)hi);
            } else if (!end) {                       // 8 real cands, all internal
                s_stale[atomicAdd(&s_stalecnt, 1)] = (u16)i;
            }
        }
        __syncthreads();

        // ---- full rescan of stale rows (one wave each, matrix row from L2/L3)
        for (int s = wid; s < s_stalecnt; s += 16) {
            const int rw  = (int)s_stale[s];
            const int c_r = (int)s_cmp[rw];
            const int rii = (int)((s_ints[rw >> 2] >> ((rw & 3) * 8)) & 255u);
            const float* Sr = S + (size_t)rw * N;
            u64 best = SENT;
            for (int k = 0; k < 16; ++k) {
                const float4 f4 = *(const float4*)(Sr + k * 256 + lane * 4);
                const u32 ip  = s_ints[k * 64 + lane];
                const u32 cq0 = ((const u32*)s_cmp)[k * 128 + lane * 2];
                const u32 cq1 = ((const u32*)s_cmp)[k * 128 + lane * 2 + 1];
                const float sv[4] = {f4.x, f4.y, f4.z, f4.w};
                #pragma unroll
                for (int m = 0; m < 4; ++m) {
                    const int j  = k * 256 + lane * 4 + m;
                    const int cj = (int)(((m < 2) ? (cq0 >> (16 * m)) : (cq1 >> (16 * (m - 2)))) & 0xFFFFu);
                    if (cj == c_r) continue;
                    const bool eq = (int)((ip >> (8 * m)) & 255u) == rii;
                    float w2; bool ex;
                    if (g == 0) { w2 = -sv[m]; ex = eq && (sv[m] != 0.0f); }
                    else { const float v = (sv[m] + (eq ? 0.0f : 0.5f)) - (eq ? 1.0f : 0.0f);
                           w2 = -v; ex = (v > 0.0f); }
                    if (!ex || j == rw) continue;
                    const u64 kk2 = ((u64)mapf(w2) << 32) | (u32)j;
                    if (kk2 < best) best = kk2;
                }
            }
            #pragma unroll
            for (int d2 = 1; d2 < 64; d2 <<= 1) { const u64 o = __shfl_xor(best, d2, 64); if (o < best) best = o; }
            if (lane == 0 && best != SENT) {
                const int j  = (int)(best & 0xFFFFFFFFu);
                const u32 wm = (u32)(best >> 32);
                const int lo = rw < j ? rw : j, hi = rw < j ? j : rw;
                atomicMin(&s_mk[c_r], ((u64)wm << 24) | ((u64)lo << 12) | (u64)hi);
            }
        }
        __syncthreads();

        // ---- merge (r7-proven star contraction, LDS edition)
        for (int c = tid; c < N; c += 1024) {        // phase 1: parents
            const u64 k = s_mk[c];
            u16 p = (u16)c;
            if (k == SENT) {
                atomicOr(&s_final[c >> 5], 1u << (c & 31));
            } else {
                const int lo = (int)((k >> 12) & 4095u), hi = (int)(k & 4095u);
                const int clo = (int)s_cmp[lo], chi = (int)s_cmp[hi];
                p = (u16)((clo == c) ? chi : clo);
            }
            s_par[c] = p;
        }
        __syncthreads();
        for (int c = tid; c < N; c += 1024) {        // phase 2: break 2-cycles
            const int d = (int)s_par[c];
            if (d != c && (int)s_par[d] == c && c < d) s_par[c] = (u16)c;
        }
        __syncthreads();
        for (int c = tid; c < N; c += 1024) {        // phase 3: dedupe + append
            const u64 k = s_mk[c];
            if (k == SENT) continue;
            s_merged = 1;                            // benign race, all write 1
            const int lo = (int)((k >> 12) & 4095u), hi = (int)(k & 4095u);
            const int clo = (int)s_cmp[lo], chi = (int)s_cmp[hi];
            const int d = (clo == c) ? chi : clo;
            const bool dup = (s_mk[d] == k) && (d < c);
            if (!dup) { const int idx = atomicAdd(&s_ecnt, 1); if (idx < EDGE_CAP) s_edge[idx] = k; }
        }
        __syncthreads();
        for (int it = 0; it < 12; ++it) {            // phase 4: pointer jumping
            for (int c = tid; c < N; c += 1024) s_par[c] = s_par[s_par[c]];
            __syncthreads();
        }
        for (int i = tid; i < N; i += 1024) s_cmp[i] = s_par[s_cmp[i]];  // phase 5
        for (int c = tid; c < N; c += 1024) s_mk[c] = SENT;
        __syncthreads();
        if (!s_merged) break;                        // uniform (post-barrier read)
    }

    // ---- count: only edges in node-0's final component
    const int r0c = (int)s_cmp[0];
    const int n   = (s_ecnt < EDGE_CAP) ? s_ecnt : EDGE_CAP;
    double A = 0.0, B = 0.0, W = 0.0;
    for (int e = tid; e < n; e += 1024) {
        const u64 k = s_edge[e];
        const int lo = (int)((k >> 12) & 4095u), hi = (int)(k & 4095u);
        if ((int)s_cmp[lo] != r0c) continue;
        const float w2 = unmapf((u32)(k >> 24));
        const bool eq = ((s_ints[lo >> 2] >> ((lo & 3) * 8)) & 255u) ==
                        ((s_ints[hi >> 2] >> ((hi & 3) * 8)) & 255u);
        if (g == 0) A += 1.0;
        else { if (eq) A += 1.0; else B += 1.0; }
        W += (double)w2;
    }
    #pragma unroll
    for (int d2 = 1; d2 < 64; d2 <<= 1) {
        A += __shfl_xor(A, d2, 64); B += __shfl_xor(B, d2, 64); W += __shfl_xor(W, d2, 64);
    }
    if (lane == 0) { s_red[wid][0] = A; s_red[wid][1] = B; s_red[wid][2] = W; }
    __syncthreads();
    if (tid == 0) {
        double a = 0, b = 0, w2 = 0;
        for (int q = 0; q < 16; ++q) { a += s_red[q][0]; b += s_red[q][1]; w2 += s_red[q][2]; }
        stats[g * 3 + 0] = a;     // gold: a (count)      | viol: b (eq count)
        stats[g * 3 + 1] = b;     // gold: unused         | viol: c (neq count)
        stats[g * 3 + 2] = w2;    // sum of edge weights
    }
}

__global__ void finalize_kernel(const double* __restrict__ ws, float* __restrict__ out)
{
    const double a = ws[0], sum_g = ws[2];
    const double b = ws[3], c = ws[4], sum_v = ws[5];
    const double gold_score = -sum_g;                 // S = -w
    const double viol_score = -sum_v + b - 0.5 * c;   // S = -w + eq - 0.5*neq
    const double delta = a - b + 0.5 * c;             // C=1, R=0.5
    const double obj   = delta + viol_score - gold_score;
    out[0] = (float)((delta > 0.0) ? fmax(0.0, obj) : 0.0);
}

extern "C" void kernel_launch(void* const* d_in, const int* in_sizes, int n_in,
                              void* d_out, int out_size, void* d_ws, size_t ws_size,
                              hipStream_t stream)
{
    const float* S       = (const float*)d_in[0];
    const int*   intents = (const int*)d_in[1];
    float*       out     = (float*)d_out;

    char* w = (char*)d_ws;
    double* stats = (double*)w;                       // 64 B
    u64*    cand  = (u64*)(w + 64);                   // 2*N*8*8 = 512 KiB

    hipLaunchKernelGGL(bv_build, dim3(256, 2), dim3(1024), 0, stream, S, intents, cand);
    hipLaunchKernelGGL(bv_rounds, dim3(2), dim3(1024), 0, stream, S, intents, cand, stats);
    hipLaunchKernelGGL(finalize_kernel, dim3(1), dim3(1), 0, stream, stats, out);
}